// Round 1
// baseline (271.094 us; speedup 1.0000x reference)
//
#include <hip/hip_runtime.h>

// ============================================================================
// AttentionWithSpatial: x@Wqkv -> masked/biased 4-head attention -> @Wout+b
// b=4, n=2048, dim=256, heads=4, dhead=64, scale=0.125
//
// Pipeline:
//  k_split : x -> xh/xl (split bf16); Wqkv -> Wqkv^T hi/lo; Wout -> Wout^T hi/lo
//  k_qkv   : qkv = x@Wqkv via 3-term split MFMA; writes q*0.125 split bf16,
//            k split bf16 (layout [b][h][n][d]), v single bf16 TRANSPOSED
//            (layout [b][h][d][n]) for conflict-light PV B-fragment loads.
//  k_attn  : flash attention. grid (qtile=64, b=4), 8 waves/block:
//            wave w -> head w&3, q-subtile w>>2 (16 rows each, QBLK=32).
//            Per KBLK=32 iter: stage K hi/lo (XOR-swizzled LDS), Vt (padded),
//            bias tile (mask? spatial : -1e30) shared by all 4 heads.
//            dots = 3-term split MFMA (fp32-grade logits); online softmax in
//            fp32 (shfl_xor over 16-lane groups); P->bf16 via LDS relayout;
//            PV single-bf16 MFMA. Epilogue writes attn-out split bf16 [m][256].
//  k_out   : out = aout@Wout + b_out via 3-term split MFMA, fp32 store.
// ============================================================================

#define B_   4
#define N_   2048
#define H_   4
#define DH_  64
#define DIMX 256
#define M_   (B_*N_)   // 8192

typedef __attribute__((ext_vector_type(8))) short short8;
typedef __attribute__((ext_vector_type(4))) float f32x4;
typedef unsigned short u16;
typedef unsigned int   u32;

#define MFMA16(a,b,c) __builtin_amdgcn_mfma_f32_16x16x32_bf16((a),(b),(c),0,0,0)

__device__ __forceinline__ u16 f2bf(float f) {
  u32 u = __builtin_bit_cast(u32, f);
  u += 0x7fffu + ((u >> 16) & 1u);   // RNE
  return (u16)(u >> 16);
}
__device__ __forceinline__ float bf2f(u16 h) {
  u32 u = ((u32)h) << 16;
  return __builtin_bit_cast(float, u);
}
__device__ __forceinline__ void split2(float f, u16* hi, u16* lo) {
  u16 h = f2bf(f);
  *hi = h;
  *lo = f2bf(f - bf2f(h));
}

// ---------------------------------------------------------------------------
// Kernel 1: split x into hi/lo bf16; transpose+split Wqkv and Wout.
// ---------------------------------------------------------------------------
__global__ __launch_bounds__(256) void k_split(
    const float* __restrict__ x, const float* __restrict__ wq,
    const float* __restrict__ wo,
    u16* __restrict__ xh, u16* __restrict__ xl,
    u16* __restrict__ wqh, u16* __restrict__ wql,
    u16* __restrict__ woh, u16* __restrict__ wol)
{
  const int NX  = M_ * DIMX;    // 2097152
  const int NWQ = 768 * 256;    // 196608
  const int NWO = 256 * 256;    // 65536
  int i = blockIdx.x * 256 + threadIdx.x;
  if (i < NX) {
    split2(x[i], &xh[i], &xl[i]);
  } else if (i < NX + NWQ) {
    int j = i - NX;
    int c = j >> 8, k = j & 255;            // out layout [c][k]
    split2(wq[k * 768 + c], &wqh[j], &wql[j]);
  } else if (i < NX + NWQ + NWO) {
    int j = i - NX - NWQ;
    int c = j >> 8, k = j & 255;
    split2(wo[k * 256 + c], &woh[j], &wol[j]);
  }
}

// ---------------------------------------------------------------------------
// Kernel 2: QKV GEMM. M=8192, N=768, K=256. Block = 4 waves, 64x64 tile.
// Wave w: rows [tileM + 16w, +16), all 64 cols. 3-term split MFMA.
// ---------------------------------------------------------------------------
__global__ __launch_bounds__(256) void k_qkv(
    const u16* __restrict__ xh, const u16* __restrict__ xl,
    const u16* __restrict__ wh, const u16* __restrict__ wl,
    u16* __restrict__ qh, u16* __restrict__ ql,
    u16* __restrict__ kh, u16* __restrict__ kl,
    u16* __restrict__ vt)
{
  const int w = threadIdx.x >> 6, lane = threadIdx.x & 63;
  const int ln = lane & 15, hb = lane >> 4;
  const int arow = blockIdx.y * 64 + w * 16 + ln;   // A-fragment row
  const int colb = blockIdx.x * 64;

  f32x4 acc[4] = {};
  for (int ks = 0; ks < 8; ++ks) {
    const int k0 = ks * 32 + hb * 8;
    short8 a_h = *(const short8*)&xh[arow * 256 + k0];
    short8 a_l = *(const short8*)&xl[arow * 256 + k0];
#pragma unroll
    for (int j = 0; j < 4; ++j) {
      const int c = colb + j * 16 + ln;
      short8 b_h = *(const short8*)&wh[c * 256 + k0];
      short8 b_l = *(const short8*)&wl[c * 256 + k0];
      acc[j] = MFMA16(a_h, b_h, acc[j]);
      acc[j] = MFMA16(a_l, b_h, acc[j]);
      acc[j] = MFMA16(a_h, b_l, acc[j]);
    }
  }
  // Epilogue: D layout col=lane&15, row=(lane>>4)*4+r
  const int mbase = blockIdx.y * 64 + w * 16 + hb * 4;
#pragma unroll
  for (int j = 0; j < 4; ++j) {
    const int c = colb + j * 16 + ln;
    const int which = c >> 8;        // 0=q 1=k 2=v
    const int hd = c & 255;
    const int hh = hd >> 6, d = hd & 63;
#pragma unroll
    for (int r = 0; r < 4; ++r) {
      const int m = mbase + r;
      const int bb = m >> 11, nn = m & 2047;
      float v = acc[j][r];
      if (which == 0) {
        const int off = ((bb * H_ + hh) * N_ + nn) * DH_ + d;
        v *= 0.125f;                           // fold in softmax scale (exact)
        split2(v, &qh[off], &ql[off]);
      } else if (which == 1) {
        const int off = ((bb * H_ + hh) * N_ + nn) * DH_ + d;
        split2(v, &kh[off], &kl[off]);
      } else {
        const int off = ((bb * H_ + hh) * DH_ + d) * N_ + nn;  // transposed
        vt[off] = f2bf(v);
      }
    }
  }
}

// ---------------------------------------------------------------------------
// Kernel 3: flash attention. grid (64 qtiles, 4 batches), 512 threads.
// ---------------------------------------------------------------------------
__global__ __launch_bounds__(512) void k_attn(
    const u16* __restrict__ qh, const u16* __restrict__ ql,
    const u16* __restrict__ khg, const u16* __restrict__ klg,
    const u16* __restrict__ vtg,
    const int* __restrict__ mask, const float* __restrict__ spat,
    u16* __restrict__ ah, u16* __restrict__ al)
{
  __shared__ __align__(16) u16   KhL[4 * 32 * 64];   // 16 KB, XOR-swizzled
  __shared__ __align__(16) u16   KlL[4 * 32 * 64];   // 16 KB
  __shared__ __align__(16) u16   VtL[4 * 64 * 40];   // 20 KB, n-padded to 40
  __shared__ __align__(16) float biasL[32 * 33];     // 4.2 KB, +1 padded
  __shared__ __align__(16) u16   PlL[8 * 16 * 40];   // 10 KB, per-wave P

  const int b = blockIdx.y, qt = blockIdx.x;
  const int tid = threadIdx.x;
  const int w = tid >> 6, lane = tid & 63;
  const int h = w & 3, qs = w >> 2;
  const int ln = lane & 15, hb = lane >> 4;

  // Q fragments (pre-scaled by 0.125 in k_qkv), hi/lo, 2 k-chunks of d
  short8 qfh[2], qfl[2];
  {
    const int qrow = qt * 32 + qs * 16 + ln;
    const int base = ((b * H_ + h) * N_ + qrow) * DH_;
    qfh[0] = *(const short8*)&qh[base + hb * 8];
    qfh[1] = *(const short8*)&qh[base + 32 + hb * 8];
    qfl[0] = *(const short8*)&ql[base + hb * 8];
    qfl[1] = *(const short8*)&ql[base + 32 + hb * 8];
  }

  f32x4 O[4] = {};
  float m_run[4] = {-1e30f, -1e30f, -1e30f, -1e30f};
  float l_run[4] = {0.f, 0.f, 0.f, 0.f};

  for (int kt = 0; kt < 64; ++kt) {
    // ---- stage K hi/lo (swizzled), Vt, bias ----
    {
      int c = tid;
#pragma unroll
      for (int it = 0; it < 2; ++it, c += 512) {   // 1024 chunks K
        const int d0 = (c & 7) * 8, n = (c >> 3) & 31, hh = c >> 8;
        const int gidx = ((b * H_ + hh) * N_ + kt * 32 + n) * DH_ + d0;
        const int li = ((hh * 32 + n) * 64 + d0) ^ ((n & 7) << 3);
        *(short8*)&KhL[li] = *(const short8*)&khg[gidx];
        *(short8*)&KlL[li] = *(const short8*)&klg[gidx];
      }
      c = tid;
#pragma unroll
      for (int it = 0; it < 2; ++it, c += 512) {   // 1024 chunks V
        const int n0 = (c & 3) * 8, d = (c >> 2) & 63, hh = c >> 8;
        const int gidx = ((b * H_ + hh) * DH_ + d) * N_ + kt * 32 + n0;
        *(short8*)&VtL[(hh * 64 + d) * 40 + n0] = *(const short8*)&vtg[gidx];
      }
      c = tid;
#pragma unroll
      for (int it = 0; it < 2; ++it, c += 512) {   // 1024 bias elems
        const int qr = c >> 5, kc = c & 31;
        const int gi = (b * N_ + qt * 32 + qr) * N_ + kt * 32 + kc;
        biasL[qr * 33 + kc] = mask[gi] ? spat[gi] : -1e30f;
      }
    }
    __syncthreads();

    // ---- QK^T (split precision): dots 16x32 per wave ----
    f32x4 dots[2] = {};
#pragma unroll
    for (int kc = 0; kc < 2; ++kc) {
#pragma unroll
      for (int j = 0; j < 2; ++j) {
        const int n = j * 16 + ln;
        const int li = ((h * 32 + n) * 64 + kc * 32 + hb * 8) ^ ((n & 7) << 3);
        short8 kfh = *(const short8*)&KhL[li];
        short8 kfl = *(const short8*)&KlL[li];
        dots[j] = MFMA16(qfh[kc], kfh, dots[j]);
        dots[j] = MFMA16(qfl[kc], kfh, dots[j]);
        dots[j] = MFMA16(qfh[kc], kfl, dots[j]);
      }
    }

    // ---- bias + mask, online softmax (rows = (lane>>4)*4 + r) ----
    float lg[2][4];
#pragma unroll
    for (int j = 0; j < 2; ++j)
#pragma unroll
      for (int r = 0; r < 4; ++r)
        lg[j][r] = dots[j][r] + biasL[(qs * 16 + hb * 4 + r) * 33 + j * 16 + ln];

    float fac[4];
#pragma unroll
    for (int r = 0; r < 4; ++r) {
      float mx = fmaxf(lg[0][r], lg[1][r]);
      mx = fmaxf(mx, __shfl_xor(mx, 1));
      mx = fmaxf(mx, __shfl_xor(mx, 2));
      mx = fmaxf(mx, __shfl_xor(mx, 4));
      mx = fmaxf(mx, __shfl_xor(mx, 8));
      const float mn = fmaxf(m_run[r], mx);
      fac[r] = __expf(m_run[r] - mn);
      m_run[r] = mn;
      const float p0 = __expf(lg[0][r] - mn);
      const float p1 = __expf(lg[1][r] - mn);
      lg[0][r] = p0; lg[1][r] = p1;
      float s = p0 + p1;
      s += __shfl_xor(s, 1);
      s += __shfl_xor(s, 2);
      s += __shfl_xor(s, 4);
      s += __shfl_xor(s, 8);
      l_run[r] = l_run[r] * fac[r] + s;
    }
#pragma unroll
    for (int j2 = 0; j2 < 4; ++j2) {
      O[j2][0] *= fac[0]; O[j2][1] *= fac[1];
      O[j2][2] *= fac[2]; O[j2][3] *= fac[3];
    }

    // ---- P (D-layout) -> LDS -> A-fragment layout, bf16 ----
#pragma unroll
    for (int j = 0; j < 2; ++j)
#pragma unroll
      for (int r = 0; r < 4; ++r)
        PlL[(w * 16 + hb * 4 + r) * 40 + j * 16 + ln] = f2bf(lg[j][r]);
    short8 pf = *(const short8*)&PlL[(w * 16 + ln) * 40 + hb * 8];

    // ---- PV ----
#pragma unroll
    for (int j2 = 0; j2 < 4; ++j2) {
      short8 vf = *(const short8*)&VtL[(h * 64 + j2 * 16 + ln) * 40 + hb * 8];
      O[j2] = MFMA16(pf, vf, O[j2]);
    }
    __syncthreads();
  }

  // ---- epilogue: normalize, write attn-out split bf16, layout [m][h*64+d]
  float inv[4];
#pragma unroll
  for (int r = 0; r < 4; ++r) inv[r] = 1.0f / l_run[r];
  const int mrow = qt * 32 + qs * 16 + hb * 4;
#pragma unroll
  for (int j2 = 0; j2 < 4; ++j2) {
    const int col = h * 64 + j2 * 16 + ln;
#pragma unroll
    for (int r = 0; r < 4; ++r) {
      const int m = b * N_ + mrow + r;
      const float v = O[j2][r] * inv[r];
      const int off = m * DIMX + col;
      split2(v, &ah[off], &al[off]);
    }
  }
}

// ---------------------------------------------------------------------------
// Kernel 4: out = aout @ Wout + b_out. M=8192, N=256, K=256.
// ---------------------------------------------------------------------------
__global__ __launch_bounds__(256) void k_out(
    const u16* __restrict__ ahg, const u16* __restrict__ alg,
    const u16* __restrict__ wh, const u16* __restrict__ wl,
    const float* __restrict__ bout, float* __restrict__ out)
{
  const int w = threadIdx.x >> 6, lane = threadIdx.x & 63;
  const int ln = lane & 15, hb = lane >> 4;
  const int arow = blockIdx.y * 64 + w * 16 + ln;
  const int colb = blockIdx.x * 64;

  f32x4 acc[4] = {};
  for (int ks = 0; ks < 8; ++ks) {
    const int k0 = ks * 32 + hb * 8;
    short8 a_h = *(const short8*)&ahg[arow * 256 + k0];
    short8 a_l = *(const short8*)&alg[arow * 256 + k0];
#pragma unroll
    for (int j = 0; j < 4; ++j) {
      const int c = colb + j * 16 + ln;
      short8 b_h = *(const short8*)&wh[c * 256 + k0];
      short8 b_l = *(const short8*)&wl[c * 256 + k0];
      acc[j] = MFMA16(a_h, b_h, acc[j]);
      acc[j] = MFMA16(a_l, b_h, acc[j]);
      acc[j] = MFMA16(a_h, b_l, acc[j]);
    }
  }
  const int mbase = blockIdx.y * 64 + w * 16 + hb * 4;
#pragma unroll
  for (int j = 0; j < 4; ++j) {
    const int c = colb + j * 16 + ln;
    const float bb = bout[c];
#pragma unroll
    for (int r = 0; r < 4; ++r)
      out[(mbase + r) * 256 + c] = acc[j][r] + bb;
  }
}

// ---------------------------------------------------------------------------
extern "C" void kernel_launch(void* const* d_in, const int* in_sizes, int n_in,
                              void* d_out, int out_size, void* d_ws, size_t ws_size,
                              hipStream_t stream)
{
  (void)in_sizes; (void)n_in; (void)out_size; (void)ws_size;
  const float* x    = (const float*)d_in[0];
  const int*   mask = (const int*)d_in[1];
  const float* spat = (const float*)d_in[2];
  const float* wq   = (const float*)d_in[3];
  const float* wo   = (const float*)d_in[4];
  const float* bout = (const float*)d_in[5];
  float* out = (float*)d_out;

  char* ws = (char*)d_ws;
  size_t o = 0;
  auto alloc = [&](size_t bytes) -> char* {
    char* p = ws + o;
    o += (bytes + 255) & ~(size_t)255;
    return p;
  };
  u16* xh  = (u16*)alloc((size_t)M_ * 256 * 2);
  u16* xl  = (u16*)alloc((size_t)M_ * 256 * 2);
  u16* wqh = (u16*)alloc((size_t)768 * 256 * 2);
  u16* wql = (u16*)alloc((size_t)768 * 256 * 2);
  u16* woh = (u16*)alloc((size_t)256 * 256 * 2);
  u16* wol = (u16*)alloc((size_t)256 * 256 * 2);
  u16* qh  = (u16*)alloc((size_t)16 * N_ * DH_ * 2);
  u16* ql  = (u16*)alloc((size_t)16 * N_ * DH_ * 2);
  u16* kh  = (u16*)alloc((size_t)16 * N_ * DH_ * 2);
  u16* kl  = (u16*)alloc((size_t)16 * N_ * DH_ * 2);
  u16* vt  = (u16*)alloc((size_t)16 * N_ * DH_ * 2);
  u16* ah  = (u16*)alloc((size_t)M_ * 256 * 2);
  u16* al  = (u16*)alloc((size_t)M_ * 256 * 2);

  hipLaunchKernelGGL(k_split, dim3(9216), dim3(256), 0, stream,
                     x, wq, wo, xh, xl, wqh, wql, woh, wol);
  hipLaunchKernelGGL(k_qkv, dim3(12, 128), dim3(256), 0, stream,
                     xh, xl, wqh, wql, qh, ql, kh, kl, vt);
  hipLaunchKernelGGL(k_attn, dim3(64, 4), dim3(512), 0, stream,
                     qh, ql, kh, kl, vt, mask, spat, ah, al);
  hipLaunchKernelGGL(k_out, dim3(4, 128), dim3(256), 0, stream,
                     ah, al, woh, wol, bout, out);
}

// Round 3
// 219.723 us; speedup vs baseline: 1.2338x; 1.2338x over previous
//
#include <hip/hip_runtime.h>

// ============================================================================
// AttentionWithSpatial: x@Wqkv -> masked/biased 4-head attention -> @Wout+b
// b=4, n=2048, dim=256, heads=4, dhead=64, scale=0.125
//
// R1: k_attn was latency-bound (0.55 TB/s, MfmaUtil 6%, 1 block/CU, serial
// stage->sync->compute->sync). This round: prefetch-to-registers (T14),
// double-buffered LDS (1 barrier/iter), exp2-domain softmax (log2e folded
// into Q prescale + bias staging), row-sum l via MFMA vs ones-fragment
// (replaces 16 shfl/iter), vectorized int2/float2 bias staging, setprio.
// R2: fix compile error (address of ext_vector element in k_split).
// ============================================================================

#define B_   4
#define N_   2048
#define H_   4
#define DH_  64
#define DIMX 256
#define M_   (B_*N_)   // 8192

#define LOG2E  1.4426950408889634f
#define NEGINF (-1e30f)

typedef __attribute__((ext_vector_type(8))) short short8;
typedef __attribute__((ext_vector_type(4))) float f32x4;
typedef unsigned short u16;
typedef unsigned int   u32;

#define MFMA16(a,b,c) __builtin_amdgcn_mfma_f32_16x16x32_bf16((a),(b),(c),0,0,0)

__device__ __forceinline__ u16 f2bf(float f) {
  u32 u = __builtin_bit_cast(u32, f);
  u += 0x7fffu + ((u >> 16) & 1u);   // RNE
  return (u16)(u >> 16);
}
__device__ __forceinline__ float bf2f(u16 h) {
  u32 u = ((u32)h) << 16;
  return __builtin_bit_cast(float, u);
}
__device__ __forceinline__ void split2(float f, u16* hi, u16* lo) {
  u16 h = f2bf(f);
  *hi = h;
  *lo = f2bf(f - bf2f(h));
}

struct u16v4 { u16 a, b, c, d; };

// ---------------------------------------------------------------------------
// Kernel 1: split x into hi/lo bf16 (float4 path); transpose+split Wqkv/Wout.
// ---------------------------------------------------------------------------
__global__ __launch_bounds__(256) void k_split(
    const float* __restrict__ x, const float* __restrict__ wq,
    const float* __restrict__ wo,
    u16* __restrict__ xh, u16* __restrict__ xl,
    u16* __restrict__ wqh, u16* __restrict__ wql,
    u16* __restrict__ woh, u16* __restrict__ wol)
{
  const int NX4 = (M_ * DIMX) / 4;  // 524288
  const int NWQ = 768 * 256;        // 196608
  const int NWO = 256 * 256;        // 65536
  int i = blockIdx.x * 256 + threadIdx.x;
  if (i < NX4) {
    const float4 v = ((const float4*)x)[i];
    u16v4 hv, lv;
    split2(v.x, &hv.a, &lv.a);
    split2(v.y, &hv.b, &lv.b);
    split2(v.z, &hv.c, &lv.c);
    split2(v.w, &hv.d, &lv.d);
    ((u16v4*)xh)[i] = hv;
    ((u16v4*)xl)[i] = lv;
  } else if (i < NX4 + NWQ) {
    int j = i - NX4;
    int c = j >> 8, k = j & 255;            // out layout [c][k]
    split2(wq[k * 768 + c], &wqh[j], &wql[j]);
  } else if (i < NX4 + NWQ + NWO) {
    int j = i - NX4 - NWQ;
    int c = j >> 8, k = j & 255;
    split2(wo[k * 256 + c], &woh[j], &wol[j]);
  }
}

// ---------------------------------------------------------------------------
// Kernel 2: QKV GEMM. M=8192, N=768, K=256. Block = 4 waves, 64x64 tile.
// Q is pre-scaled by 0.125*log2e (softmax moves to exp2 domain).
// ---------------------------------------------------------------------------
__global__ __launch_bounds__(256) void k_qkv(
    const u16* __restrict__ xh, const u16* __restrict__ xl,
    const u16* __restrict__ wh, const u16* __restrict__ wl,
    u16* __restrict__ qh, u16* __restrict__ ql,
    u16* __restrict__ kh, u16* __restrict__ kl,
    u16* __restrict__ vt)
{
  const int w = threadIdx.x >> 6, lane = threadIdx.x & 63;
  const int ln = lane & 15, hb = lane >> 4;
  const int arow = blockIdx.y * 64 + w * 16 + ln;
  const int colb = blockIdx.x * 64;

  f32x4 acc[4] = {};
  for (int ks = 0; ks < 8; ++ks) {
    const int k0 = ks * 32 + hb * 8;
    short8 a_h = *(const short8*)&xh[arow * 256 + k0];
    short8 a_l = *(const short8*)&xl[arow * 256 + k0];
#pragma unroll
    for (int j = 0; j < 4; ++j) {
      const int c = colb + j * 16 + ln;
      short8 b_h = *(const short8*)&wh[c * 256 + k0];
      short8 b_l = *(const short8*)&wl[c * 256 + k0];
      acc[j] = MFMA16(a_h, b_h, acc[j]);
      acc[j] = MFMA16(a_l, b_h, acc[j]);
      acc[j] = MFMA16(a_h, b_l, acc[j]);
    }
  }
  const int mbase = blockIdx.y * 64 + w * 16 + hb * 4;
#pragma unroll
  for (int j = 0; j < 4; ++j) {
    const int c = colb + j * 16 + ln;
    const int which = c >> 8;        // 0=q 1=k 2=v
    const int hd = c & 255;
    const int hh = hd >> 6, d = hd & 63;
#pragma unroll
    for (int r = 0; r < 4; ++r) {
      const int m = mbase + r;
      const int bb = m >> 11, nn = m & 2047;
      float v = acc[j][r];
      if (which == 0) {
        const int off = ((bb * H_ + hh) * N_ + nn) * DH_ + d;
        v *= (0.125f * LOG2E);                 // scale + exp2-domain fold
        split2(v, &qh[off], &ql[off]);
      } else if (which == 1) {
        const int off = ((bb * H_ + hh) * N_ + nn) * DH_ + d;
        split2(v, &kh[off], &kl[off]);
      } else {
        const int off = ((bb * H_ + hh) * DH_ + d) * N_ + nn;  // transposed
        vt[off] = f2bf(v);
      }
    }
  }
}

// ---------------------------------------------------------------------------
// Kernel 3: flash attention. grid (64 qtiles, 4 batches), 512 threads.
// Pipelined: prefetch tile kt+1 to regs, compute tile kt from LDS buf[kt&1],
// store prefetch to buf[(kt+1)&1], single barrier per iteration.
// ---------------------------------------------------------------------------
__global__ __launch_bounds__(512) void k_attn(
    const u16* __restrict__ qhg, const u16* __restrict__ qlg,
    const u16* __restrict__ khg, const u16* __restrict__ klg,
    const u16* __restrict__ vtg,
    const int* __restrict__ mask, const float* __restrict__ spat,
    u16* __restrict__ ah, u16* __restrict__ al)
{
  __shared__ __align__(16) u16   KhL[2][4 * 32 * 64];   // 2 x 16 KB swizzled
  __shared__ __align__(16) u16   KlL[2][4 * 32 * 64];   // 2 x 16 KB
  __shared__ __align__(16) u16   VtL[2][4 * 64 * 40];   // 2 x 20 KB, pad 40
  __shared__ __align__(16) float biasL[2][32 * 34];     // 2 x 4.25 KB
  __shared__ __align__(16) u16   PlL[8 * 16 * 40];      // 10 KB per-wave P

  const int b = blockIdx.y, qt = blockIdx.x;
  const int tid = threadIdx.x;
  const int w = tid >> 6, lane = tid & 63;
  const int h = w & 3, qs = w >> 2;
  const int ln = lane & 15, hb = lane >> 4;

  // ---- fixed staging geometry per thread ----
  int koff[2], kli[2], voff[2], vli[2];
#pragma unroll
  for (int i = 0; i < 2; ++i) {
    const int c = tid + i * 512;
    { const int d0 = (c & 7) * 8, n = (c >> 3) & 31, hh = c >> 8;
      koff[i] = ((b * H_ + hh) * N_ + n) * DH_ + d0;
      kli[i]  = ((hh * 32 + n) * 64 + d0) ^ ((n & 7) << 3); }
    { const int n0 = (c & 3) * 8, d = (c >> 2) & 63, hh = c >> 8;
      voff[i] = ((b * H_ + hh) * DH_ + d) * N_ + n0;
      vli[i]  = (hh * 64 + d) * 40 + n0; }
  }
  const int qr  = tid >> 4, kc2 = (tid & 15) * 2;
  const int boff = (b * N_ + qt * 32 + qr) * N_ + kc2;
  const int bli  = qr * 34 + kc2;

  // ---- Q fragments (pre-scaled by 0.125*log2e), hi/lo ----
  short8 qfh[2], qfl[2];
  {
    const int qrow = qt * 32 + qs * 16 + ln;
    const int base = ((b * H_ + h) * N_ + qrow) * DH_;
    qfh[0] = *(const short8*)&qhg[base + hb * 8];
    qfh[1] = *(const short8*)&qhg[base + 32 + hb * 8];
    qfl[0] = *(const short8*)&qlg[base + hb * 8];
    qfl[1] = *(const short8*)&qlg[base + 32 + hb * 8];
  }

  short8 ones;
#pragma unroll
  for (int i = 0; i < 8; ++i) ones[i] = (short)0x3F80;   // bf16 1.0

  f32x4 O[4] = {};
  f32x4 l_acc = {};
  float m_run[4] = {NEGINF, NEGINF, NEGINF, NEGINF};

  short8 pKh[2], pKl[2], pV[2];
  int2 pM; float2 pS;

  // ---- prologue: stage tile 0 into buf 0 ----
#pragma unroll
  for (int i = 0; i < 2; ++i) {
    pKh[i] = *(const short8*)&khg[koff[i]];
    pKl[i] = *(const short8*)&klg[koff[i]];
    pV[i]  = *(const short8*)&vtg[voff[i]];
  }
  pM = *(const int2*)&mask[boff];
  pS = *(const float2*)&spat[boff];
#pragma unroll
  for (int i = 0; i < 2; ++i) {
    *(short8*)&KhL[0][kli[i]] = pKh[i];
    *(short8*)&KlL[0][kli[i]] = pKl[i];
    *(short8*)&VtL[0][vli[i]] = pV[i];
  }
  {
    float2 bv;
    bv.x = pM.x ? pS.x * LOG2E : NEGINF;
    bv.y = pM.y ? pS.y * LOG2E : NEGINF;
    *(float2*)&biasL[0][bli] = bv;
  }
  __syncthreads();

  for (int kt = 0; kt < 64; ++kt) {
    const int cur = kt & 1;
    const int ktn = (kt + 1) & 63;   // last iter redundantly reloads tile 0

    // ---- issue prefetch for next tile (latency hides under compute) ----
#pragma unroll
    for (int i = 0; i < 2; ++i) {
      pKh[i] = *(const short8*)&khg[koff[i] + ktn * 2048];
      pKl[i] = *(const short8*)&klg[koff[i] + ktn * 2048];
      pV[i]  = *(const short8*)&vtg[voff[i] + ktn * 32];
    }
    pM = *(const int2*)&mask[boff + ktn * 32];
    pS = *(const float2*)&spat[boff + ktn * 32];

    // ---- QK^T (split precision, exp2-domain logits) ----
    const u16* Kh = KhL[cur];
    const u16* Kl = KlL[cur];
    f32x4 dots[2] = {};
    __builtin_amdgcn_s_setprio(1);
#pragma unroll
    for (int kc = 0; kc < 2; ++kc)
#pragma unroll
      for (int j = 0; j < 2; ++j) {
        const int n = j * 16 + ln;
        const int li = ((h * 32 + n) * 64 + kc * 32 + hb * 8) ^ ((n & 7) << 3);
        short8 kfh = *(const short8*)&Kh[li];
        short8 kfl = *(const short8*)&Kl[li];
        dots[j] = MFMA16(qfh[kc], kfh, dots[j]);
        dots[j] = MFMA16(qfl[kc], kfh, dots[j]);
        dots[j] = MFMA16(qfh[kc], kfl, dots[j]);
      }
    __builtin_amdgcn_s_setprio(0);

    // ---- bias add + online softmax (exp2 domain) ----
    const float* Bb = biasL[cur];
    float lg[2][4];
#pragma unroll
    for (int j = 0; j < 2; ++j)
#pragma unroll
      for (int r = 0; r < 4; ++r)
        lg[j][r] = dots[j][r] + Bb[(qs * 16 + hb * 4 + r) * 34 + j * 16 + ln];

    float fac[4];
#pragma unroll
    for (int r = 0; r < 4; ++r) {
      float mx = fmaxf(lg[0][r], lg[1][r]);
      mx = fmaxf(mx, __shfl_xor(mx, 1));
      mx = fmaxf(mx, __shfl_xor(mx, 2));
      mx = fmaxf(mx, __shfl_xor(mx, 4));
      mx = fmaxf(mx, __shfl_xor(mx, 8));
      const float mn = fmaxf(m_run[r], mx);
      fac[r] = exp2f(m_run[r] - mn);
      m_run[r] = mn;
      lg[0][r] = exp2f(lg[0][r] - mn);
      lg[1][r] = exp2f(lg[1][r] - mn);
    }
#pragma unroll
    for (int j2 = 0; j2 < 4; ++j2) {
      O[j2][0] *= fac[0]; O[j2][1] *= fac[1];
      O[j2][2] *= fac[2]; O[j2][3] *= fac[3];
    }
    l_acc[0] *= fac[0]; l_acc[1] *= fac[1];
    l_acc[2] *= fac[2]; l_acc[3] *= fac[3];

    // ---- P (D-layout) -> LDS -> A-fragment layout, bf16 ----
#pragma unroll
    for (int j = 0; j < 2; ++j)
#pragma unroll
      for (int r = 0; r < 4; ++r)
        PlL[(w * 16 + hb * 4 + r) * 40 + j * 16 + ln] = f2bf(lg[j][r]);
    short8 pf = *(const short8*)&PlL[(w * 16 + ln) * 40 + hb * 8];

    // ---- PV + row-sum via ones-fragment MFMA ----
    const u16* Vt = VtL[cur];
    __builtin_amdgcn_s_setprio(1);
#pragma unroll
    for (int j2 = 0; j2 < 4; ++j2) {
      short8 vf = *(const short8*)&Vt[(h * 64 + j2 * 16 + ln) * 40 + hb * 8];
      O[j2] = MFMA16(pf, vf, O[j2]);
    }
    l_acc = MFMA16(pf, ones, l_acc);
    __builtin_amdgcn_s_setprio(0);

    // ---- store prefetched tile into the other buffer ----
    const int nxt = cur ^ 1;
#pragma unroll
    for (int i = 0; i < 2; ++i) {
      *(short8*)&KhL[nxt][kli[i]] = pKh[i];
      *(short8*)&KlL[nxt][kli[i]] = pKl[i];
      *(short8*)&VtL[nxt][vli[i]] = pV[i];
    }
    {
      float2 bv;
      bv.x = pM.x ? pS.x * LOG2E : NEGINF;
      bv.y = pM.y ? pS.y * LOG2E : NEGINF;
      *(float2*)&biasL[nxt][bli] = bv;
    }
    __syncthreads();
  }

  // ---- epilogue: normalize, write attn-out split bf16, layout [m][h*64+d]
  float inv[4];
#pragma unroll
  for (int r = 0; r < 4; ++r) inv[r] = 1.0f / l_acc[r];
  const int mrow = qt * 32 + qs * 16 + hb * 4;
#pragma unroll
  for (int j2 = 0; j2 < 4; ++j2) {
    const int col = h * 64 + j2 * 16 + ln;
#pragma unroll
    for (int r = 0; r < 4; ++r) {
      const int m = b * N_ + mrow + r;
      const float v = O[j2][r] * inv[r];
      split2(v, &ah[m * DIMX + col], &al[m * DIMX + col]);
    }
  }
}

// ---------------------------------------------------------------------------
// Kernel 4: out = aout @ Wout + b_out. M=8192, N=256, K=256.
// ---------------------------------------------------------------------------
__global__ __launch_bounds__(256) void k_out(
    const u16* __restrict__ ahg, const u16* __restrict__ alg,
    const u16* __restrict__ wh, const u16* __restrict__ wl,
    const float* __restrict__ bout, float* __restrict__ out)
{
  const int w = threadIdx.x >> 6, lane = threadIdx.x & 63;
  const int ln = lane & 15, hb = lane >> 4;
  const int arow = blockIdx.y * 64 + w * 16 + ln;
  const int colb = blockIdx.x * 64;

  f32x4 acc[4] = {};
  for (int ks = 0; ks < 8; ++ks) {
    const int k0 = ks * 32 + hb * 8;
    short8 a_h = *(const short8*)&ahg[arow * 256 + k0];
    short8 a_l = *(const short8*)&alg[arow * 256 + k0];
#pragma unroll
    for (int j = 0; j < 4; ++j) {
      const int c = colb + j * 16 + ln;
      short8 b_h = *(const short8*)&wh[c * 256 + k0];
      short8 b_l = *(const short8*)&wl[c * 256 + k0];
      acc[j] = MFMA16(a_h, b_h, acc[j]);
      acc[j] = MFMA16(a_l, b_h, acc[j]);
      acc[j] = MFMA16(a_h, b_l, acc[j]);
    }
  }
  const int mbase = blockIdx.y * 64 + w * 16 + hb * 4;
#pragma unroll
  for (int j = 0; j < 4; ++j) {
    const int c = colb + j * 16 + ln;
    const float bb = bout[c];
#pragma unroll
    for (int r = 0; r < 4; ++r)
      out[(mbase + r) * 256 + c] = acc[j][r] + bb;
  }
}

// ---------------------------------------------------------------------------
extern "C" void kernel_launch(void* const* d_in, const int* in_sizes, int n_in,
                              void* d_out, int out_size, void* d_ws, size_t ws_size,
                              hipStream_t stream)
{
  (void)in_sizes; (void)n_in; (void)out_size; (void)ws_size;
  const float* x    = (const float*)d_in[0];
  const int*   mask = (const int*)d_in[1];
  const float* spat = (const float*)d_in[2];
  const float* wq   = (const float*)d_in[3];
  const float* wo   = (const float*)d_in[4];
  const float* bout = (const float*)d_in[5];
  float* out = (float*)d_out;

  char* ws = (char*)d_ws;
  size_t o = 0;
  auto alloc = [&](size_t bytes) -> char* {
    char* p = ws + o;
    o += (bytes + 255) & ~(size_t)255;
    return p;
  };
  u16* xh  = (u16*)alloc((size_t)M_ * 256 * 2);
  u16* xl  = (u16*)alloc((size_t)M_ * 256 * 2);
  u16* wqh = (u16*)alloc((size_t)768 * 256 * 2);
  u16* wql = (u16*)alloc((size_t)768 * 256 * 2);
  u16* woh = (u16*)alloc((size_t)256 * 256 * 2);
  u16* wol = (u16*)alloc((size_t)256 * 256 * 2);
  u16* qh  = (u16*)alloc((size_t)16 * N_ * DH_ * 2);
  u16* ql  = (u16*)alloc((size_t)16 * N_ * DH_ * 2);
  u16* kh  = (u16*)alloc((size_t)16 * N_ * DH_ * 2);
  u16* kl  = (u16*)alloc((size_t)16 * N_ * DH_ * 2);
  u16* vt  = (u16*)alloc((size_t)16 * N_ * DH_ * 2);
  u16* ah  = (u16*)alloc((size_t)M_ * 256 * 2);
  u16* al  = (u16*)alloc((size_t)M_ * 256 * 2);

  hipLaunchKernelGGL(k_split, dim3(3072), dim3(256), 0, stream,
                     x, wq, wo, xh, xl, wqh, wql, woh, wol);
  hipLaunchKernelGGL(k_qkv, dim3(12, 128), dim3(256), 0, stream,
                     xh, xl, wqh, wql, qh, ql, kh, kl, vt);
  hipLaunchKernelGGL(k_attn, dim3(64, 4), dim3(512), 0, stream,
                     qh, ql, kh, kl, vt, mask, spat, ah, al);
  hipLaunchKernelGGL(k_out, dim3(4, 128), dim3(256), 0, stream,
                     ah, al, woh, wol, bout, out);
}

// Round 4
// 169.234 us; speedup vs baseline: 1.6019x; 1.2983x over previous
//
#include <hip/hip_runtime.h>

// ============================================================================
// AttentionWithSpatial: x@Wqkv -> masked/biased 4-head attention -> @Wout+b
// b=4, n=2048, dim=256, heads=4, dhead=64, scale=0.125
//
// R3: k_attn was LDS-pipe-bound (~196KB LDS traffic/iter/block, 6.8M bank
// conflicts) + barrier-coupled. This round:
//  - K/V direct global->reg in FRAGMENT-MAJOR layout (no LDS staging; L2-fit
//    per-XCD via bijective XCD swizzle: 2 XCDs per batch).
//  - dropped K-lo split term (error ~0.003 in exp2-domain logits, negligible).
//  - swapped QK^T (mfma(K,Q)): per-lane q-row softmax (2 shfl_xor, scalar m),
//    vectorized fragment-ordered bias tile, tiny P-exchange LDS roundtrip.
//  - T13 defer-max (THR=8): O-rescale only on trigger iters.
//  - grid 512 (4 waves/block, qtile=16) -> 2 blocks/CU, LDS ~9KB.
// ============================================================================

#define B_   4
#define N_   2048
#define H_   4
#define DH_  64
#define DIMX 256
#define M_   (B_*N_)   // 8192

#define LOG2E  1.4426950408889634f
#define NEGINF (-1e30f)
#define DEFER_THR 8.0f

typedef __attribute__((ext_vector_type(8))) short short8;
typedef __attribute__((ext_vector_type(4))) float f32x4;
typedef unsigned short u16;
typedef unsigned int   u32;

#define MFMA16(a,b,c) __builtin_amdgcn_mfma_f32_16x16x32_bf16((a),(b),(c),0,0,0)

__device__ __forceinline__ u16 f2bf(float f) {
  u32 u = __builtin_bit_cast(u32, f);
  u += 0x7fffu + ((u >> 16) & 1u);   // RNE
  return (u16)(u >> 16);
}
__device__ __forceinline__ float bf2f(u16 h) {
  u32 u = ((u32)h) << 16;
  return __builtin_bit_cast(float, u);
}
__device__ __forceinline__ void split2(float f, u16* hi, u16* lo) {
  u16 h = f2bf(f);
  *hi = h;
  *lo = f2bf(f - bf2f(h));
}
__device__ __forceinline__ float bpermf(int srclane, float v) {
  return __builtin_bit_cast(float,
      __builtin_amdgcn_ds_bpermute(srclane << 2, __builtin_bit_cast(int, v)));
}
__device__ __forceinline__ u32 cvtpk(float lo, float hi) {
  u32 r;
  asm("v_cvt_pk_bf16_f32 %0, %1, %2" : "=v"(r) : "v"(lo), "v"(hi));
  return r;
}

struct u16v4 { u16 a, b, c, d; };

// ---------------------------------------------------------------------------
// Kernel 1: split x into hi/lo bf16 (float4 path); transpose+split Wqkv/Wout.
// ---------------------------------------------------------------------------
__global__ __launch_bounds__(256) void k_split(
    const float* __restrict__ x, const float* __restrict__ wq,
    const float* __restrict__ wo,
    u16* __restrict__ xh, u16* __restrict__ xl,
    u16* __restrict__ wqh, u16* __restrict__ wql,
    u16* __restrict__ woh, u16* __restrict__ wol)
{
  const int NX4 = (M_ * DIMX) / 4;  // 524288
  const int NWQ = 768 * 256;        // 196608
  const int NWO = 256 * 256;        // 65536
  int i = blockIdx.x * 256 + threadIdx.x;
  if (i < NX4) {
    const float4 v = ((const float4*)x)[i];
    u16v4 hv, lv;
    split2(v.x, &hv.a, &lv.a);
    split2(v.y, &hv.b, &lv.b);
    split2(v.z, &hv.c, &lv.c);
    split2(v.w, &hv.d, &lv.d);
    ((u16v4*)xh)[i] = hv;
    ((u16v4*)xl)[i] = lv;
  } else if (i < NX4 + NWQ) {
    int j = i - NX4;
    int c = j >> 8, k = j & 255;            // out layout [c][k]
    split2(wq[k * 768 + c], &wqh[j], &wql[j]);
  } else if (i < NX4 + NWQ + NWO) {
    int j = i - NX4 - NWQ;
    int c = j >> 8, k = j & 255;
    split2(wo[k * 256 + c], &woh[j], &wol[j]);
  }
}

// ---------------------------------------------------------------------------
// Kernel 2: QKV GEMM. M=8192, N=768, K=256. Block = 4 waves, 64x64 tile.
// Q pre-scaled by 0.125*log2e, split hi/lo, layout [bh][n][d].
// K single bf16, FRAGMENT-MAJOR: [(bh*64+kt)*4 + kc*2+j]*512 + lane*8 + e
//   where lane=(hb*16+ln) holds K[n=kt*32+j*16+ln][d=kc*32+hb*8+e].
// V single bf16, FRAGMENT-MAJOR: [(bh*64+kt)*4 + j2]*512 + lane*8 + e
//   where lane holds V[n=kt*32+hb*8+e][d=j2*16+ln]  (V^T fragments).
// ---------------------------------------------------------------------------
__global__ __launch_bounds__(256) void k_qkv(
    const u16* __restrict__ xh, const u16* __restrict__ xl,
    const u16* __restrict__ wh, const u16* __restrict__ wl,
    u16* __restrict__ qh, u16* __restrict__ ql,
    u16* __restrict__ kf, u16* __restrict__ vf)
{
  const int w = threadIdx.x >> 6, lane = threadIdx.x & 63;
  const int ln = lane & 15, hb = lane >> 4;
  const int arow = blockIdx.y * 64 + w * 16 + ln;
  const int colb = blockIdx.x * 64;

  f32x4 acc[4] = {};
  for (int ks = 0; ks < 8; ++ks) {
    const int k0 = ks * 32 + hb * 8;
    short8 a_h = *(const short8*)&xh[arow * 256 + k0];
    short8 a_l = *(const short8*)&xl[arow * 256 + k0];
#pragma unroll
    for (int j = 0; j < 4; ++j) {
      const int c = colb + j * 16 + ln;
      short8 b_h = *(const short8*)&wh[c * 256 + k0];
      short8 b_l = *(const short8*)&wl[c * 256 + k0];
      acc[j] = MFMA16(a_h, b_h, acc[j]);
      acc[j] = MFMA16(a_l, b_h, acc[j]);
      acc[j] = MFMA16(a_h, b_l, acc[j]);
    }
  }
  const int mbase = blockIdx.y * 64 + w * 16 + hb * 4;
#pragma unroll
  for (int j = 0; j < 4; ++j) {
    const int c = colb + j * 16 + ln;
    const int which = c >> 8;        // 0=q 1=k 2=v
    const int hd = c & 255;
    const int hh = hd >> 6, d = hd & 63;
#pragma unroll
    for (int r = 0; r < 4; ++r) {
      const int m = mbase + r;
      const int bb = m >> 11, nn = m & 2047;
      const int bh = bb * H_ + hh;
      float v = acc[j][r];
      if (which == 0) {
        const int off = (bh * N_ + nn) * DH_ + d;
        v *= (0.125f * LOG2E);                 // scale + exp2-domain fold
        split2(v, &qh[off], &ql[off]);
      } else if (which == 1) {
        const int ktile = nn >> 5, jj = (nn >> 4) & 1, lnn = nn & 15;
        const int kc = d >> 5, hbb = (d >> 3) & 3, e = d & 7;
        const int off = (bh * 64 + ktile) * 2048 + (kc * 2 + jj) * 512
                      + (hbb * 16 + lnn) * 8 + e;
        kf[off] = f2bf(v);
      } else {
        const int ktile = nn >> 5, hbb = (nn >> 3) & 3, e = nn & 7;
        const int j2 = d >> 4, lnn = d & 15;
        const int off = (bh * 64 + ktile) * 2048 + j2 * 512
                      + (hbb * 16 + lnn) * 8 + e;
        vf[off] = f2bf(v);
      }
    }
  }
}

// ---------------------------------------------------------------------------
// Kernel 3: flash attention. Flat grid 512, 256 threads (4 waves = 4 heads),
// qtile = 16 rows. XCD-swizzled so each XCD serves one batch (K/V L2-fit).
// K/V: coalesced fragment loads global->reg, double-buffered in regs.
// Swapped QK^T; per-lane softmax; defer-max; P exchange via tiny LDS.
// ---------------------------------------------------------------------------
__global__ __launch_bounds__(256) void k_attn(
    const u16* __restrict__ qhg, const u16* __restrict__ qlg,
    const u16* __restrict__ kfg, const u16* __restrict__ vfg,
    const int* __restrict__ mask, const float* __restrict__ spat,
    u16* __restrict__ ah, u16* __restrict__ al)
{
  __shared__ __align__(16) float biasL[2][512];  // fragged: (j*64+lane)*4+r
  __shared__ __align__(16) u32   Pbuf[4][320];   // per-wave, stride 20 u32/row

  const int bid = blockIdx.x;
  const int xcd = bid & 7, idx = bid >> 3;
  const int b = xcd >> 1;                  // 2 XCDs per batch
  const int qt = idx * 2 + (xcd & 1);      // bijective, qt in [0,128)

  const int tid = threadIdx.x;
  const int w = tid >> 6, lane = tid & 63; // wave = head
  const int ln = lane & 15, hb = lane >> 4;
  const int bh = b * H_ + w;

  // ---- Q fragments (pre-scaled by 0.125*log2e), hi/lo ----
  short8 qfh[2], qfl[2];
  {
    const int base = (bh * N_ + qt * 16 + ln) * DH_;
    qfh[0] = *(const short8*)&qhg[base + hb * 8];
    qfh[1] = *(const short8*)&qhg[base + 32 + hb * 8];
    qfl[0] = *(const short8*)&qlg[base + hb * 8];
    qfl[1] = *(const short8*)&qlg[base + 32 + hb * 8];
  }

  // ---- bias staging geometry: thread -> (row=tid&15, k2=(tid>>4)*2) ----
  const int srow = tid & 15;
  const int sk2 = (tid >> 4) * 2;
  const int boff = (b * N_ + qt * 16 + srow) * N_ + sk2;
  const int bli = (((sk2 >> 4) * 64) + (((sk2 >> 2) & 3) * 16) + srow) * 4
                + (sk2 & 3);

  const u16* Kbase = kfg + (size_t)(bh * 64) * 2048;
  const u16* Vbase = vfg + (size_t)(bh * 64) * 2048;
  const int l8 = lane * 8;

  short8 ones;
#pragma unroll
  for (int i = 0; i < 8; ++i) ones[i] = (short)0x3F80;   // bf16 1.0

  f32x4 O[4] = {};
  f32x4 l_acc = {};
  float m_run = NEGINF;

  short8 Kc[4], Vc[4], Kn[4], Vn[4];
  int2 pM; float2 pS;

  // ---- prologue: tile 0 K/V to regs, bias tile 0 to LDS[0] ----
#pragma unroll
  for (int i = 0; i < 4; ++i) {
    Kc[i] = *(const short8*)&Kbase[(0 * 4 + i) * 512 + l8];
    Vc[i] = *(const short8*)&Vbase[(0 * 4 + i) * 512 + l8];
  }
  {
    int2 m0 = *(const int2*)&mask[boff];
    float2 s0 = *(const float2*)&spat[boff];
    float2 bv;
    bv.x = m0.x ? s0.x * LOG2E : NEGINF;
    bv.y = m0.y ? s0.y * LOG2E : NEGINF;
    *(float2*)&biasL[0][bli] = bv;
  }
  __syncthreads();

  for (int kt = 0; kt < 64; ++kt) {
    const int cur = kt & 1;
    const int ktn = (kt + 1) & 63;   // last iter redundantly reloads tile 0

    // ---- issue next-tile loads (hide under compute) ----
    {
      const u16* Kt = Kbase + ktn * 2048;
      const u16* Vt = Vbase + ktn * 2048;
#pragma unroll
      for (int i = 0; i < 4; ++i) {
        Kn[i] = *(const short8*)&Kt[i * 512 + l8];
        Vn[i] = *(const short8*)&Vt[i * 512 + l8];
      }
      pM = *(const int2*)&mask[boff + ktn * 32];
      pS = *(const float2*)&spat[boff + ktn * 32];
    }

    // ---- swapped QK^T: dots[j] lane(hb,ln) = S[k=j*16+hb*4+r][q=ln] ----
    f32x4 dots[2] = {};
    __builtin_amdgcn_s_setprio(1);
#pragma unroll
    for (int kc = 0; kc < 2; ++kc) {
#pragma unroll
      for (int j = 0; j < 2; ++j) {
        dots[j] = MFMA16(Kc[kc * 2 + j], qfh[kc], dots[j]);
        dots[j] = MFMA16(Kc[kc * 2 + j], qfl[kc], dots[j]);
      }
    }
    __builtin_amdgcn_s_setprio(0);

    // ---- bias add (vectorized fragment-ordered read) ----
    float lg[2][4];
#pragma unroll
    for (int j = 0; j < 2; ++j) {
      const f32x4 bs = *(const f32x4*)&biasL[cur][(j * 64 + lane) * 4];
#pragma unroll
      for (int r = 0; r < 4; ++r) lg[j][r] = dots[j][r] + bs[r];
    }

    // ---- per-lane online softmax (q = ln), defer-max THR=8 ----
    float pmax = fmaxf(fmaxf(fmaxf(lg[0][0], lg[0][1]), fmaxf(lg[0][2], lg[0][3])),
                       fmaxf(fmaxf(lg[1][0], lg[1][1]), fmaxf(lg[1][2], lg[1][3])));
    pmax = fmaxf(pmax, __shfl_xor(pmax, 16));
    pmax = fmaxf(pmax, __shfl_xor(pmax, 32));
    if (__any(pmax > m_run + DEFER_THR)) {
      const float mn = fmaxf(m_run, pmax);
      const float fac = exp2f(m_run - mn);
      m_run = mn;
#pragma unroll
      for (int r = 0; r < 4; ++r) {
        const float fr = bpermf(hb * 4 + r, fac);  // fac of q-row hb*4+r
        O[0][r] *= fr; O[1][r] *= fr; O[2][r] *= fr; O[3][r] *= fr;
        l_acc[r] *= fr;
      }
    }
    float p[2][4];
#pragma unroll
    for (int j = 0; j < 2; ++j)
#pragma unroll
      for (int r = 0; r < 4; ++r)
        p[j][r] = exp2f(lg[j][r] - m_run);

    // ---- pack bf16 pairs + exchange to A-fragment via per-wave LDS ----
    u32* Pw = &Pbuf[w][0];
    {
      uint2 w0, w1;
      w0.x = cvtpk(p[0][0], p[0][1]); w0.y = cvtpk(p[0][2], p[0][3]);
      w1.x = cvtpk(p[1][0], p[1][1]); w1.y = cvtpk(p[1][2], p[1][3]);
      *(uint2*)&Pw[ln * 20 + hb * 2]     = w0;   // kp = 0*8 + hb*2 + {0,1}
      *(uint2*)&Pw[ln * 20 + 8 + hb * 2] = w1;   // kp = 1*8 + hb*2 + {0,1}
    }
    const short8 pf = *(const short8*)&Pw[ln * 20 + hb * 4];  // kp=hb*4..+3

    // ---- PV + row-sum via ones-MFMA ----
    __builtin_amdgcn_s_setprio(1);
#pragma unroll
    for (int j2 = 0; j2 < 4; ++j2)
      O[j2] = MFMA16(pf, Vc[j2], O[j2]);
    l_acc = MFMA16(pf, ones, l_acc);
    __builtin_amdgcn_s_setprio(0);

    // ---- stage bias for next tile ----
    {
      float2 bv;
      bv.x = pM.x ? pS.x * LOG2E : NEGINF;
      bv.y = pM.y ? pS.y * LOG2E : NEGINF;
      *(float2*)&biasL[cur ^ 1][bli] = bv;
    }
    __syncthreads();

#pragma unroll
    for (int i = 0; i < 4; ++i) { Kc[i] = Kn[i]; Vc[i] = Vn[i]; }
  }

  // ---- epilogue: normalize, write attn-out split bf16, layout [m][h*64+d]
  float inv[4];
#pragma unroll
  for (int r = 0; r < 4; ++r) inv[r] = 1.0f / l_acc[r];
  const int mrow = b * N_ + qt * 16 + hb * 4;
#pragma unroll
  for (int j2 = 0; j2 < 4; ++j2) {
    const int col = w * 64 + j2 * 16 + ln;
#pragma unroll
    for (int r = 0; r < 4; ++r) {
      const float v = O[j2][r] * inv[r];
      split2(v, &ah[(mrow + r) * DIMX + col], &al[(mrow + r) * DIMX + col]);
    }
  }
}

// ---------------------------------------------------------------------------
// Kernel 4: out = aout @ Wout + b_out. M=8192, N=256, K=256.
// ---------------------------------------------------------------------------
__global__ __launch_bounds__(256) void k_out(
    const u16* __restrict__ ahg, const u16* __restrict__ alg,
    const u16* __restrict__ wh, const u16* __restrict__ wl,
    const float* __restrict__ bout, float* __restrict__ out)
{
  const int w = threadIdx.x >> 6, lane = threadIdx.x & 63;
  const int ln = lane & 15, hb = lane >> 4;
  const int arow = blockIdx.y * 64 + w * 16 + ln;
  const int colb = blockIdx.x * 64;

  f32x4 acc[4] = {};
  for (int ks = 0; ks < 8; ++ks) {
    const int k0 = ks * 32 + hb * 8;
    short8 a_h = *(const short8*)&ahg[arow * 256 + k0];
    short8 a_l = *(const short8*)&alg[arow * 256 + k0];
#pragma unroll
    for (int j = 0; j < 4; ++j) {
      const int c = colb + j * 16 + ln;
      short8 b_h = *(const short8*)&wh[c * 256 + k0];
      short8 b_l = *(const short8*)&wl[c * 256 + k0];
      acc[j] = MFMA16(a_h, b_h, acc[j]);
      acc[j] = MFMA16(a_l, b_h, acc[j]);
      acc[j] = MFMA16(a_h, b_l, acc[j]);
    }
  }
  const int mbase = blockIdx.y * 64 + w * 16 + hb * 4;
#pragma unroll
  for (int j = 0; j < 4; ++j) {
    const int c = colb + j * 16 + ln;
    const float bb = bout[c];
#pragma unroll
    for (int r = 0; r < 4; ++r)
      out[(mbase + r) * 256 + c] = acc[j][r] + bb;
  }
}

// ---------------------------------------------------------------------------
extern "C" void kernel_launch(void* const* d_in, const int* in_sizes, int n_in,
                              void* d_out, int out_size, void* d_ws, size_t ws_size,
                              hipStream_t stream)
{
  (void)in_sizes; (void)n_in; (void)out_size; (void)ws_size;
  const float* x    = (const float*)d_in[0];
  const int*   mask = (const int*)d_in[1];
  const float* spat = (const float*)d_in[2];
  const float* wq   = (const float*)d_in[3];
  const float* wo   = (const float*)d_in[4];
  const float* bout = (const float*)d_in[5];
  float* out = (float*)d_out;

  char* ws = (char*)d_ws;
  size_t o = 0;
  auto alloc = [&](size_t bytes) -> char* {
    char* p = ws + o;
    o += (bytes + 255) & ~(size_t)255;
    return p;
  };
  u16* xh  = (u16*)alloc((size_t)M_ * 256 * 2);
  u16* xl  = (u16*)alloc((size_t)M_ * 256 * 2);
  u16* wqh = (u16*)alloc((size_t)768 * 256 * 2);
  u16* wql = (u16*)alloc((size_t)768 * 256 * 2);
  u16* woh = (u16*)alloc((size_t)256 * 256 * 2);
  u16* wol = (u16*)alloc((size_t)256 * 256 * 2);
  u16* qh  = (u16*)alloc((size_t)16 * N_ * DH_ * 2);
  u16* ql  = (u16*)alloc((size_t)16 * N_ * DH_ * 2);
  u16* kf  = (u16*)alloc((size_t)16 * N_ * DH_ * 2);
  u16* vf  = (u16*)alloc((size_t)16 * N_ * DH_ * 2);
  u16* ah  = (u16*)alloc((size_t)M_ * 256 * 2);
  u16* al  = (u16*)alloc((size_t)M_ * 256 * 2);

  hipLaunchKernelGGL(k_split, dim3(3072), dim3(256), 0, stream,
                     x, wq, wo, xh, xl, wqh, wql, woh, wol);
  hipLaunchKernelGGL(k_qkv, dim3(12, 128), dim3(256), 0, stream,
                     xh, xl, wqh, wql, qh, ql, kf, vf);
  hipLaunchKernelGGL(k_attn, dim3(512), dim3(256), 0, stream,
                     qh, ql, kf, vf, mask, spat, ah, al);
  hipLaunchKernelGGL(k_out, dim3(4, 128), dim3(256), 0, stream,
                     ah, al, woh, wol, bout, out);
}